// Round 7
// baseline (78.251 us; speedup 1.0000x reference)
//
#include <hip/hip_runtime.h>
#include <stdint.h>
#include <stddef.h>

#define NCELLS (512 * 512)   // 262144 grid cells
#define CG 64                // grid embedding channels
#define CPC 64               // point-cloud channels
#define CIN 128              // concat width
#define CH 32                // hidden width
#define COUT 3

// Fully-fused linear network: out = W_eff @ [emb; pc] + b_eff,
// W_eff = Z_w@Y_w (3x128), b_eff = Z_w@Y_b + Z_b.
// GZ8[p] = bf16x4-packed (W_eff[:, :64] @ grid[:, p] + b_eff)  -- 2 MiB table
// main:   out[i] = unpack(GZ8[idx[i]]) + W_eff[:, 64:] @ pc[i]
//
// main structure (all-lane): each wave owns 64 consecutive points/iteration.
// Every lane loads its OWN idx and its OWN 8B gather (64 gathers in flight
// per wave). All 16 pc float4 loads per iteration are front-loaded into
// statically-indexed register arrays (one issue burst, one vmcnt wait),
// then 8 k-steps of group-FMA + 8-lane shuffle reduce. Plain (cached) loads
// for pc/idx -- NT only on out stores and the gz grid stream, protecting the
// GZ table's L2 residency without deprioritizing our own read stream.

typedef float f32x4 __attribute__((ext_vector_type(4)));

__device__ inline unsigned int pack2_bf16_rne(float a, float b) {
    unsigned int ua = __float_as_uint(a);
    unsigned int ub = __float_as_uint(b);
    ua = (ua + 0x7fffu + ((ua >> 16) & 1u)) >> 16;
    ub = (ub + 0x7fffu + ((ub >> 16) & 1u)) >> 16;
    return ua | (ub << 16);
}
__device__ inline float bf16_lo(unsigned int v) { return __uint_as_float(v << 16); }
__device__ inline float bf16_hi(unsigned int v) { return __uint_as_float(v & 0xffff0000u); }

// ---------------------------------------------------------------------------
// GZ table builder (fused-weight prep recomputed per block into LDS).
// 1024 blocks x 256 threads, 1 cell/thread; grid reads NT (zero reuse).
// ---------------------------------------------------------------------------
__global__ void __launch_bounds__(256)
gz_kernel(const float* __restrict__ grid,   // (64, 262144)
          const float* __restrict__ Yw,     // (32,128)
          const float* __restrict__ Yb,     // (32,)
          const float* __restrict__ Zw,     // (3,32)
          const float* __restrict__ Zb,     // (3,)
          uint2* __restrict__ GZ8) {
    __shared__ float4 sW[CG];
    __shared__ float  sB[3];
    const int t = threadIdx.x;

    if (t < CG) {
        float w0 = 0.f, w1 = 0.f, w2 = 0.f;
#pragma unroll
        for (int j = 0; j < CH; ++j) {
            float y = Yw[j * CIN + t];
            w0 = fmaf(Zw[0 * CH + j], y, w0);
            w1 = fmaf(Zw[1 * CH + j], y, w1);
            w2 = fmaf(Zw[2 * CH + j], y, w2);
        }
        sW[t] = make_float4(w0, w1, w2, 0.f);
    } else if (t == CG) {
        float b0 = Zb[0], b1 = Zb[1], b2 = Zb[2];
#pragma unroll
        for (int j = 0; j < CH; ++j) {
            float y = Yb[j];
            b0 = fmaf(Zw[0 * CH + j], y, b0);
            b1 = fmaf(Zw[1 * CH + j], y, b1);
            b2 = fmaf(Zw[2 * CH + j], y, b2);
        }
        sB[0] = b0; sB[1] = b1; sB[2] = b2;
    }
    __syncthreads();

    const int p = blockIdx.x * 256 + t;
    float a0 = sB[0], a1 = sB[1], a2 = sB[2];

#pragma unroll 8
    for (int c = 0; c < CG; ++c) {
        float g = __builtin_nontemporal_load(grid + (size_t)c * NCELLS + p);
        float4 w = sW[c];
        a0 = fmaf(w.x, g, a0);
        a1 = fmaf(w.y, g, a1);
        a2 = fmaf(w.z, g, a2);
    }
    GZ8[p] = make_uint2(pack2_bf16_rne(a0, a1), pack2_bf16_rne(a2, 0.f));
}

// ---------------------------------------------------------------------------
// Main kernel (all-lane, front-loaded; see header comment).
// ---------------------------------------------------------------------------
__global__ void __launch_bounds__(256)
main_kernel(const uint2* __restrict__ GZ8,
            const float* __restrict__ pc,       // (N,64)
            const void* __restrict__ idx_raw,
            const float* __restrict__ Yw,       // (32,128)
            const float* __restrict__ Zw,       // (3,32)
            float* __restrict__ out, int N) {
    __shared__ float4 sW[CG];
    __shared__ int    sFlag;
    const int t = threadIdx.x;

    if (t < CG) {
        // fused pc-weight column 64+t:  W_eff[:,64+t]
        float w0 = 0.f, w1 = 0.f, w2 = 0.f;
#pragma unroll
        for (int j = 0; j < CH; ++j) {
            float y = Yw[j * CIN + CG + t];
            w0 = fmaf(Zw[0 * CH + j], y, w0);
            w1 = fmaf(Zw[1 * CH + j], y, w1);
            w2 = fmaf(Zw[2 * CH + j], y, w2);
        }
        sW[t] = make_float4(w0, w1, w2, 0.f);
    } else if (t == CG) {
        // idx element width: int64 values are < 2^18, so aligned u64 reads of
        // an int64 array are tiny; for int32 they merge two random indices.
        int is64 = 1;
        for (int i = 0; i < 8; ++i) {
            if (((const unsigned long long*)idx_raw)[i] >= (unsigned long long)NCELLS) {
                is64 = 0; break;
            }
        }
        sFlag = is64;
    }
    __syncthreads();

    const int ls  = t & 7;                      // lane-in-group
    const int l63 = t & 63;                     // lane-in-wave = group*8 + ls
    const int gw8 = l63 & ~7;                   // group offset within wave
    const int is64 = sFlag;                     // uniform

    // this lane's 8-channel weight slice (channels 4*ls..4*ls+3, 32+4*ls..)
    const float4 wA0 = sW[4 * ls + 0];
    const float4 wA1 = sW[4 * ls + 1];
    const float4 wA2 = sW[4 * ls + 2];
    const float4 wA3 = sW[4 * ls + 3];
    const float4 wB0 = sW[32 + 4 * ls + 0];
    const float4 wB1 = sW[32 + 4 * ls + 1];
    const float4 wB2 = sW[32 + 4 * ls + 2];
    const float4 wB3 = sW[32 + 4 * ls + 3];

    const long long wave_id = (long long)blockIdx.x * (blockDim.x >> 6) + (t >> 6);
    const long long nwaves  = (long long)gridDim.x * (blockDim.x >> 6);

    for (long long wbase = wave_id * 64; wbase < N; wbase += nwaves * 64) {
        const long long pm = wbase + l63;       // this lane's own point
        const bool full = (wbase + 64 <= N);

        // ---- all-lane idx load + gather (64 in flight per wave) ----
        uint2 gz8 = make_uint2(0u, 0u);
        if (full || pm < N) {
            int idx;
            if (is64) idx = (int)(((const long long*)idx_raw)[pm]);
            else      idx = ((const int*)idx_raw)[pm];
            gz8 = GZ8[idx];                     // L2/L3-resident 2MB table
        }

        // ---- front-load ALL pc reads for the 8 k-steps (issue burst) ----
        f32x4 xlo[8], xhi[8];
#pragma unroll
        for (int k = 0; k < 8; ++k) {
            const long long pk = wbase + gw8 + k;
            if (full || pk < N) {
                const float* prow = pc + (size_t)pk * CPC;
                xlo[k] = *(const f32x4*)(prow + 4 * ls);
                xhi[k] = *(const f32x4*)(prow + 32 + 4 * ls);
            } else {
                xlo[k] = (f32x4)0.f; xhi[k] = (f32x4)0.f;
            }
        }

        float r0 = 0.f, r1 = 0.f, r2 = 0.f;

#pragma unroll
        for (int k = 0; k < 8; ++k) {
            f32x4 x0 = xlo[k], x1 = xhi[k];
            float a0, a1, a2;
            a0 = wA0.x * x0.x;            a1 = wA0.y * x0.x;            a2 = wA0.z * x0.x;
            a0 = fmaf(wA1.x, x0.y, a0);   a1 = fmaf(wA1.y, x0.y, a1);   a2 = fmaf(wA1.z, x0.y, a2);
            a0 = fmaf(wA2.x, x0.z, a0);   a1 = fmaf(wA2.y, x0.z, a1);   a2 = fmaf(wA2.z, x0.z, a2);
            a0 = fmaf(wA3.x, x0.w, a0);   a1 = fmaf(wA3.y, x0.w, a1);   a2 = fmaf(wA3.z, x0.w, a2);
            a0 = fmaf(wB0.x, x1.x, a0);   a1 = fmaf(wB0.y, x1.x, a1);   a2 = fmaf(wB0.z, x1.x, a2);
            a0 = fmaf(wB1.x, x1.y, a0);   a1 = fmaf(wB1.y, x1.y, a1);   a2 = fmaf(wB1.z, x1.y, a2);
            a0 = fmaf(wB2.x, x1.z, a0);   a1 = fmaf(wB2.y, x1.z, a1);   a2 = fmaf(wB2.z, x1.z, a2);
            a0 = fmaf(wB3.x, x1.w, a0);   a1 = fmaf(wB3.y, x1.w, a1);   a2 = fmaf(wB3.z, x1.w, a2);

#pragma unroll
            for (int m = 1; m < 8; m <<= 1) {
                a0 += __shfl_xor(a0, m, 8);
                a1 += __shfl_xor(a1, m, 8);
                a2 += __shfl_xor(a2, m, 8);
            }

            // lane k of the group keeps point k's result (cndmask, no branch)
            if (ls == k) { r0 = a0; r1 = a1; r2 = a2; }
        }

        if (full || pm < N) {
            float* o = out + (size_t)pm * COUT;
            __builtin_nontemporal_store(r0 + bf16_lo(gz8.x), o + 0);
            __builtin_nontemporal_store(r1 + bf16_hi(gz8.x), o + 1);
            __builtin_nontemporal_store(r2 + bf16_lo(gz8.y), o + 2);
        }
    }
}

// ---------------------------------------------------------------------------
// Fallback if workspace < 2 MiB (shouldn't happen). Direct strided gather.
// ---------------------------------------------------------------------------
__global__ void __launch_bounds__(256)
direct_kernel(const float* __restrict__ grid,
              const float* __restrict__ pc,
              const void* __restrict__ idx_raw,
              const float* __restrict__ Yw, const float* __restrict__ Yb,
              const float* __restrict__ Zw, const float* __restrict__ Zb,
              float* __restrict__ out, int N) {
    int i = blockIdx.x * blockDim.x + threadIdx.x;
    if (i >= N) return;
    int idx = (int)(((const long long*)idx_raw)[i]);   // reference spec: int64

    float h[CH];
#pragma unroll
    for (int j = 0; j < CH; ++j) h[j] = Yb[j];
    for (int c = 0; c < CG; ++c) {
        float g = grid[(size_t)c * NCELLS + idx];
#pragma unroll
        for (int j = 0; j < CH; ++j) h[j] = fmaf(Yw[j * CIN + c], g, h[j]);
    }
    const float4* pcp = (const float4*)(pc + (size_t)i * CPC);
#pragma unroll 2
    for (int c4 = 0; c4 < CPC / 4; ++c4) {
        float4 x = pcp[c4];
#pragma unroll
        for (int j = 0; j < CH; ++j) {
            const float* w = Yw + j * CIN + CG + c4 * 4;
            h[j] = fmaf(w[0], x.x, h[j]); h[j] = fmaf(w[1], x.y, h[j]);
            h[j] = fmaf(w[2], x.z, h[j]); h[j] = fmaf(w[3], x.w, h[j]);
        }
    }
#pragma unroll
    for (int t = 0; t < COUT; ++t) {
        float a = Zb[t];
#pragma unroll
        for (int j = 0; j < CH; ++j) a = fmaf(Zw[t * CH + j], h[j], a);
        out[(size_t)i * COUT + t] = a;
    }
}

extern "C" void kernel_launch(void* const* d_in, const int* in_sizes, int n_in,
                              void* d_out, int out_size, void* d_ws, size_t ws_size,
                              hipStream_t stream) {
    const float* grid = (const float*)d_in[0];   // (64,512,512)
    const float* pc   = (const float*)d_in[1];   // (N,64)
    const void*  idx  = d_in[2];                 // (N,) int64 (or int32, detected)
    const float* Yw   = (const float*)d_in[3];   // (32,128)
    const float* Yb   = (const float*)d_in[4];   // (32,)
    const float* Zw   = (const float*)d_in[5];   // (3,32)
    const float* Zb   = (const float*)d_in[6];   // (3,)
    float* out = (float*)d_out;
    const int N = in_sizes[2];

    const size_t GZ_bytes = (size_t)NCELLS * sizeof(uint2);   // 2 MiB

    if (ws_size >= GZ_bytes && N >= 16) {
        uint2* GZ8 = (uint2*)d_ws;
        gz_kernel<<<NCELLS / 256, 256, 0, stream>>>(grid, Yw, Yb, Zw, Zb, GZ8);
        // 2048 blocks = 8192 waves; each wave handles 64 consecutive points
        // per iteration (~1.9 iterations at N=1M).
        main_kernel<<<2048, 256, 0, stream>>>(GZ8, pc, idx, Yw, Zw, out, N);
    } else {
        const int threads = 256;
        direct_kernel<<<(N + threads - 1) / threads, threads, 0, stream>>>(
            grid, pc, idx, Yw, Yb, Zw, Zb, out, N);
    }
}

// Round 9
// 70.549 us; speedup vs baseline: 1.1092x; 1.1092x over previous
//
#include <hip/hip_runtime.h>
#include <stdint.h>
#include <stddef.h>

#define NCELLS (512 * 512)   // 262144 grid cells
#define CG 64                // grid embedding channels
#define CPC 64               // point-cloud channels
#define CIN 128              // concat width
#define CH 32                // hidden width
#define COUT 3

// Fully-fused linear network: out = W_eff @ [emb; pc] + b_eff,
// W_eff = Z_w@Y_w (3x128), b_eff = Z_w@Y_b + Z_b.
// GZ8[p] = bf16x4-packed (W_eff[:, :64] @ grid[:, p] + b_eff)  -- 2 MiB table
// main:   out[i] = unpack(GZ8[idx[i]]) + W_eff[:, 64:] @ pc[i]
//
// main structure (R6-proven all-lane core, ONE tile per wave): each wave owns
// 64 consecutive points; every lane loads its OWN idx + 8B gather (64 gathers
// in flight/wave, issued at wave start and overlapped across resident waves);
// 8-lane groups cooperate on the dot products (interleaved NT pc loads + FMA
// + 8-lane shuffle reduce); lane k keeps point k's sum; 3 NT dword stores per
// owning lane. No grid-stride loop -> no exposed second-tile gather chain.

typedef float f32x4 __attribute__((ext_vector_type(4)));

__device__ inline f32x4 nt_load4(const float* p) {
    return __builtin_nontemporal_load((const f32x4*)p);
}
__device__ inline unsigned int pack2_bf16_rne(float a, float b) {
    unsigned int ua = __float_as_uint(a);
    unsigned int ub = __float_as_uint(b);
    ua = (ua + 0x7fffu + ((ua >> 16) & 1u)) >> 16;
    ub = (ub + 0x7fffu + ((ub >> 16) & 1u)) >> 16;
    return ua | (ub << 16);
}
__device__ inline float bf16_lo(unsigned int v) { return __uint_as_float(v << 16); }
__device__ inline float bf16_hi(unsigned int v) { return __uint_as_float(v & 0xffff0000u); }

// ---------------------------------------------------------------------------
// GZ table builder (fused-weight prep recomputed per block into LDS).
// 1024 blocks x 256 threads, 1 cell/thread; grid reads NT (zero reuse).
// ---------------------------------------------------------------------------
__global__ void __launch_bounds__(256)
gz_kernel(const float* __restrict__ grid,   // (64, 262144)
          const float* __restrict__ Yw,     // (32,128)
          const float* __restrict__ Yb,     // (32,)
          const float* __restrict__ Zw,     // (3,32)
          const float* __restrict__ Zb,     // (3,)
          uint2* __restrict__ GZ8) {
    __shared__ float4 sW[CG];
    __shared__ float  sB[3];
    const int t = threadIdx.x;

    if (t < CG) {
        float w0 = 0.f, w1 = 0.f, w2 = 0.f;
#pragma unroll
        for (int j = 0; j < CH; ++j) {
            float y = Yw[j * CIN + t];
            w0 = fmaf(Zw[0 * CH + j], y, w0);
            w1 = fmaf(Zw[1 * CH + j], y, w1);
            w2 = fmaf(Zw[2 * CH + j], y, w2);
        }
        sW[t] = make_float4(w0, w1, w2, 0.f);
    } else if (t == CG) {
        float b0 = Zb[0], b1 = Zb[1], b2 = Zb[2];
#pragma unroll
        for (int j = 0; j < CH; ++j) {
            float y = Yb[j];
            b0 = fmaf(Zw[0 * CH + j], y, b0);
            b1 = fmaf(Zw[1 * CH + j], y, b1);
            b2 = fmaf(Zw[2 * CH + j], y, b2);
        }
        sB[0] = b0; sB[1] = b1; sB[2] = b2;
    }
    __syncthreads();

    const int p = blockIdx.x * 256 + t;
    float a0 = sB[0], a1 = sB[1], a2 = sB[2];

#pragma unroll 8
    for (int c = 0; c < CG; ++c) {
        float g = __builtin_nontemporal_load(grid + (size_t)c * NCELLS + p);
        float4 w = sW[c];
        a0 = fmaf(w.x, g, a0);
        a1 = fmaf(w.y, g, a1);
        a2 = fmaf(w.z, g, a2);
    }
    GZ8[p] = make_uint2(pack2_bf16_rne(a0, a1), pack2_bf16_rne(a2, 0.f));
}

// ---------------------------------------------------------------------------
// Main kernel (all-lane core, one 64-point tile per wave; see header).
// ---------------------------------------------------------------------------
__global__ void __launch_bounds__(256)
main_kernel(const uint2* __restrict__ GZ8,
            const float* __restrict__ pc,       // (N,64)
            const void* __restrict__ idx_raw,
            const float* __restrict__ Yw,       // (32,128)
            const float* __restrict__ Zw,       // (3,32)
            float* __restrict__ out, int N) {
    __shared__ float4 sW[CG];
    __shared__ int    sFlag;
    const int t = threadIdx.x;

    if (t < CG) {
        // fused pc-weight column 64+t:  W_eff[:,64+t]
        float w0 = 0.f, w1 = 0.f, w2 = 0.f;
#pragma unroll
        for (int j = 0; j < CH; ++j) {
            float y = Yw[j * CIN + CG + t];
            w0 = fmaf(Zw[0 * CH + j], y, w0);
            w1 = fmaf(Zw[1 * CH + j], y, w1);
            w2 = fmaf(Zw[2 * CH + j], y, w2);
        }
        sW[t] = make_float4(w0, w1, w2, 0.f);
    } else if (t == CG) {
        // idx element width: int64 values are < 2^18, so aligned u64 reads of
        // an int64 array are tiny; for int32 they merge two random indices.
        int is64 = 1;
        for (int i = 0; i < 8; ++i) {
            if (((const unsigned long long*)idx_raw)[i] >= (unsigned long long)NCELLS) {
                is64 = 0; break;
            }
        }
        sFlag = is64;
    }
    __syncthreads();

    const int ls  = t & 7;                      // lane-in-group
    const int l63 = t & 63;                     // lane-in-wave = group*8 + ls
    const int gw8 = l63 & ~7;                   // group offset within wave
    const int is64 = sFlag;                     // uniform

    // this wave's single 64-point tile
    const long long wbase =
        ((long long)blockIdx.x * (blockDim.x >> 6) + (t >> 6)) * 64;
    if (wbase >= N) return;
    const bool full = (wbase + 64 <= N);
    const long long pm = wbase + l63;           // this lane's own point

    // this lane's 8-channel weight slice (channels 4*ls..4*ls+3, 32+4*ls..)
    const float4 wA0 = sW[4 * ls + 0];
    const float4 wA1 = sW[4 * ls + 1];
    const float4 wA2 = sW[4 * ls + 2];
    const float4 wA3 = sW[4 * ls + 3];
    const float4 wB0 = sW[32 + 4 * ls + 0];
    const float4 wB1 = sW[32 + 4 * ls + 1];
    const float4 wB2 = sW[32 + 4 * ls + 2];
    const float4 wB3 = sW[32 + 4 * ls + 3];

    // ---- all-lane idx load + gather (64 in flight per wave, issued first) ----
    uint2 gz8 = make_uint2(0u, 0u);
    if (full || pm < N) {
        int idx;
        if (is64) idx = (int)__builtin_nontemporal_load((const long long*)idx_raw + pm);
        else      idx = __builtin_nontemporal_load((const int*)idx_raw + pm);
        gz8 = GZ8[idx];                         // L2/L3-resident 2MB table
    }

    float r0 = 0.f, r1 = 0.f, r2 = 0.f;

#pragma unroll
    for (int k = 0; k < 8; ++k) {
        const long long pk = wbase + gw8 + k;   // group's point this step
        f32x4 x0, x1;
        if (full || pk < N) {
            const float* prow = pc + (size_t)pk * CPC;
            x0 = nt_load4(prow + 4 * ls);
            x1 = nt_load4(prow + 32 + 4 * ls);
        } else {
            x0 = (f32x4)0.f; x1 = (f32x4)0.f;
        }

        float a0, a1, a2;
        a0 = wA0.x * x0.x;            a1 = wA0.y * x0.x;            a2 = wA0.z * x0.x;
        a0 = fmaf(wA1.x, x0.y, a0);   a1 = fmaf(wA1.y, x0.y, a1);   a2 = fmaf(wA1.z, x0.y, a2);
        a0 = fmaf(wA2.x, x0.z, a0);   a1 = fmaf(wA2.y, x0.z, a1);   a2 = fmaf(wA2.z, x0.z, a2);
        a0 = fmaf(wA3.x, x0.w, a0);   a1 = fmaf(wA3.y, x0.w, a1);   a2 = fmaf(wA3.z, x0.w, a2);
        a0 = fmaf(wB0.x, x1.x, a0);   a1 = fmaf(wB0.y, x1.x, a1);   a2 = fmaf(wB0.z, x1.x, a2);
        a0 = fmaf(wB1.x, x1.y, a0);   a1 = fmaf(wB1.y, x1.y, a1);   a2 = fmaf(wB1.z, x1.y, a2);
        a0 = fmaf(wB2.x, x1.z, a0);   a1 = fmaf(wB2.y, x1.z, a1);   a2 = fmaf(wB2.z, x1.z, a2);
        a0 = fmaf(wB3.x, x1.w, a0);   a1 = fmaf(wB3.y, x1.w, a1);   a2 = fmaf(wB3.z, x1.w, a2);

#pragma unroll
        for (int m = 1; m < 8; m <<= 1) {
            a0 += __shfl_xor(a0, m, 8);
            a1 += __shfl_xor(a1, m, 8);
            a2 += __shfl_xor(a2, m, 8);
        }

        // lane k of the group keeps point k's result (cndmask, no branch)
        if (ls == k) { r0 = a0; r1 = a1; r2 = a2; }
    }

    if (full || pm < N) {
        float* o = out + (size_t)pm * COUT;
        __builtin_nontemporal_store(r0 + bf16_lo(gz8.x), o + 0);
        __builtin_nontemporal_store(r1 + bf16_hi(gz8.x), o + 1);
        __builtin_nontemporal_store(r2 + bf16_lo(gz8.y), o + 2);
    }
}

// ---------------------------------------------------------------------------
// Fallback if workspace < 2 MiB (shouldn't happen). Direct strided gather.
// ---------------------------------------------------------------------------
__global__ void __launch_bounds__(256)
direct_kernel(const float* __restrict__ grid,
              const float* __restrict__ pc,
              const void* __restrict__ idx_raw,
              const float* __restrict__ Yw, const float* __restrict__ Yb,
              const float* __restrict__ Zw, const float* __restrict__ Zb,
              float* __restrict__ out, int N) {
    int i = blockIdx.x * blockDim.x + threadIdx.x;
    if (i >= N) return;
    int idx = (int)(((const long long*)idx_raw)[i]);   // reference spec: int64

    float h[CH];
#pragma unroll
    for (int j = 0; j < CH; ++j) h[j] = Yb[j];
    for (int c = 0; c < CG; ++c) {
        float g = grid[(size_t)c * NCELLS + idx];
#pragma unroll
        for (int j = 0; j < CH; ++j) h[j] = fmaf(Yw[j * CIN + c], g, h[j]);
    }
    const float4* pcp = (const float4*)(pc + (size_t)i * CPC);
#pragma unroll 2
    for (int c4 = 0; c4 < CPC / 4; ++c4) {
        float4 x = pcp[c4];
#pragma unroll
        for (int j = 0; j < CH; ++j) {
            const float* w = Yw + j * CIN + CG + c4 * 4;
            h[j] = fmaf(w[0], x.x, h[j]); h[j] = fmaf(w[1], x.y, h[j]);
            h[j] = fmaf(w[2], x.z, h[j]); h[j] = fmaf(w[3], x.w, h[j]);
        }
    }
#pragma unroll
    for (int t = 0; t < COUT; ++t) {
        float a = Zb[t];
#pragma unroll
        for (int j = 0; j < CH; ++j) a = fmaf(Zw[t * CH + j], h[j], a);
        out[(size_t)i * COUT + t] = a;
    }
}

extern "C" void kernel_launch(void* const* d_in, const int* in_sizes, int n_in,
                              void* d_out, int out_size, void* d_ws, size_t ws_size,
                              hipStream_t stream) {
    const float* grid = (const float*)d_in[0];   // (64,512,512)
    const float* pc   = (const float*)d_in[1];   // (N,64)
    const void*  idx  = d_in[2];                 // (N,) int64 (or int32, detected)
    const float* Yw   = (const float*)d_in[3];   // (32,128)
    const float* Yb   = (const float*)d_in[4];   // (32,)
    const float* Zw   = (const float*)d_in[5];   // (3,32)
    const float* Zb   = (const float*)d_in[6];   // (3,)
    float* out = (float*)d_out;
    const int N = in_sizes[2];

    const size_t GZ_bytes = (size_t)NCELLS * sizeof(uint2);   // 2 MiB

    if (ws_size >= GZ_bytes && N >= 16) {
        uint2* GZ8 = (uint2*)d_ws;
        gz_kernel<<<NCELLS / 256, 256, 0, stream>>>(grid, Yw, Yb, Zw, Zb, GZ8);
        // one 64-point tile per wave; 4 waves/block -> 256 points per block
        const int blocks = (int)((N + 255) / 256);
        main_kernel<<<blocks, 256, 0, stream>>>(GZ8, pc, idx, Yw, Zw, out, N);
    } else {
        const int threads = 256;
        direct_kernel<<<(N + threads - 1) / threads, threads, 0, stream>>>(
            grid, pc, idx, Yw, Yb, Zw, Zb, out, N);
    }
}

// Round 10
// 67.774 us; speedup vs baseline: 1.1546x; 1.0409x over previous
//
#include <hip/hip_runtime.h>
#include <stdint.h>
#include <stddef.h>

#define NCELLS (512 * 512)   // 262144 grid cells
#define CG 64                // grid embedding channels
#define CPC 64               // point-cloud channels
#define CIN 128              // concat width
#define CH 32                // hidden width
#define COUT 3

// Fully-fused linear network: out = W_eff @ [emb; pc] + b_eff,
// W_eff = Z_w@Y_w (3x128), b_eff = Z_w@Y_b + Z_b.
// GZ8[p] = bf16x4-packed (W_eff[:, :64] @ grid[:, p] + b_eff)  -- 2 MiB table
// main:   out[i] = unpack(GZ8[idx[i]]) + W_eff[:, 64:] @ pc[i]
//
// main structure (all-lane, R6-validated 67.9us): each wave owns 64
// consecutive points/iteration. Every lane loads its OWN idx (one 512B
// coalesced load/wave) and its OWN 8B gather (64 gathers in flight/wave --
// request-rate-optimal: the random gather is 1 line-request/point by
// construction). 8-lane groups cooperate on dot products, k=0..7 points per
// group; lane k keeps point k's sum. NT on all streaming traffic (pc, idx,
// grid, out) protects the GZ table's L2 residency. Grid-stride, 2048 blocks.

typedef float f32x4 __attribute__((ext_vector_type(4)));

__device__ inline f32x4 nt_load4(const float* p) {
    return __builtin_nontemporal_load((const f32x4*)p);
}
__device__ inline unsigned int pack2_bf16_rne(float a, float b) {
    unsigned int ua = __float_as_uint(a);
    unsigned int ub = __float_as_uint(b);
    ua = (ua + 0x7fffu + ((ua >> 16) & 1u)) >> 16;
    ub = (ub + 0x7fffu + ((ub >> 16) & 1u)) >> 16;
    return ua | (ub << 16);
}
__device__ inline float bf16_lo(unsigned int v) { return __uint_as_float(v << 16); }
__device__ inline float bf16_hi(unsigned int v) { return __uint_as_float(v & 0xffff0000u); }

// ---------------------------------------------------------------------------
// GZ table builder (fused-weight prep recomputed per block into LDS).
// 1024 blocks x 256 threads, 1 cell/thread; grid reads NT (zero reuse).
// ---------------------------------------------------------------------------
__global__ void __launch_bounds__(256)
gz_kernel(const float* __restrict__ grid,   // (64, 262144)
          const float* __restrict__ Yw,     // (32,128)
          const float* __restrict__ Yb,     // (32,)
          const float* __restrict__ Zw,     // (3,32)
          const float* __restrict__ Zb,     // (3,)
          uint2* __restrict__ GZ8) {
    __shared__ float4 sW[CG];
    __shared__ float  sB[3];
    const int t = threadIdx.x;

    if (t < CG) {
        float w0 = 0.f, w1 = 0.f, w2 = 0.f;
#pragma unroll
        for (int j = 0; j < CH; ++j) {
            float y = Yw[j * CIN + t];
            w0 = fmaf(Zw[0 * CH + j], y, w0);
            w1 = fmaf(Zw[1 * CH + j], y, w1);
            w2 = fmaf(Zw[2 * CH + j], y, w2);
        }
        sW[t] = make_float4(w0, w1, w2, 0.f);
    } else if (t == CG) {
        float b0 = Zb[0], b1 = Zb[1], b2 = Zb[2];
#pragma unroll
        for (int j = 0; j < CH; ++j) {
            float y = Yb[j];
            b0 = fmaf(Zw[0 * CH + j], y, b0);
            b1 = fmaf(Zw[1 * CH + j], y, b1);
            b2 = fmaf(Zw[2 * CH + j], y, b2);
        }
        sB[0] = b0; sB[1] = b1; sB[2] = b2;
    }
    __syncthreads();

    const int p = blockIdx.x * 256 + t;
    float a0 = sB[0], a1 = sB[1], a2 = sB[2];

#pragma unroll 8
    for (int c = 0; c < CG; ++c) {
        float g = __builtin_nontemporal_load(grid + (size_t)c * NCELLS + p);
        float4 w = sW[c];
        a0 = fmaf(w.x, g, a0);
        a1 = fmaf(w.y, g, a1);
        a2 = fmaf(w.z, g, a2);
    }
    GZ8[p] = make_uint2(pack2_bf16_rne(a0, a1), pack2_bf16_rne(a2, 0.f));
}

// ---------------------------------------------------------------------------
// Main kernel (all-lane; see header comment).
// ---------------------------------------------------------------------------
__global__ void __launch_bounds__(256)
main_kernel(const uint2* __restrict__ GZ8,
            const float* __restrict__ pc,       // (N,64)
            const void* __restrict__ idx_raw,
            const float* __restrict__ Yw,       // (32,128)
            const float* __restrict__ Zw,       // (3,32)
            float* __restrict__ out, int N) {
    __shared__ float4 sW[CG];
    __shared__ int    sFlag;
    const int t = threadIdx.x;

    if (t < CG) {
        // fused pc-weight column 64+t:  W_eff[:,64+t]
        float w0 = 0.f, w1 = 0.f, w2 = 0.f;
#pragma unroll
        for (int j = 0; j < CH; ++j) {
            float y = Yw[j * CIN + CG + t];
            w0 = fmaf(Zw[0 * CH + j], y, w0);
            w1 = fmaf(Zw[1 * CH + j], y, w1);
            w2 = fmaf(Zw[2 * CH + j], y, w2);
        }
        sW[t] = make_float4(w0, w1, w2, 0.f);
    } else if (t == CG) {
        // idx element width: int64 values are < 2^18, so aligned u64 reads of
        // an int64 array are tiny; for int32 they merge two random indices.
        int is64 = 1;
        for (int i = 0; i < 8; ++i) {
            if (((const unsigned long long*)idx_raw)[i] >= (unsigned long long)NCELLS) {
                is64 = 0; break;
            }
        }
        sFlag = is64;
    }
    __syncthreads();

    const int ls  = t & 7;                      // lane-in-group
    const int l63 = t & 63;                     // lane-in-wave = group*8 + ls
    const int gw8 = l63 & ~7;                   // group offset within wave
    const int is64 = sFlag;                     // uniform

    // this lane's 8-channel weight slice (channels 4*ls..4*ls+3, 32+4*ls..)
    const float4 wA0 = sW[4 * ls + 0];
    const float4 wA1 = sW[4 * ls + 1];
    const float4 wA2 = sW[4 * ls + 2];
    const float4 wA3 = sW[4 * ls + 3];
    const float4 wB0 = sW[32 + 4 * ls + 0];
    const float4 wB1 = sW[32 + 4 * ls + 1];
    const float4 wB2 = sW[32 + 4 * ls + 2];
    const float4 wB3 = sW[32 + 4 * ls + 3];

    const long long wave_id = (long long)blockIdx.x * (blockDim.x >> 6) + (t >> 6);
    const long long nwaves  = (long long)gridDim.x * (blockDim.x >> 6);

    for (long long wbase = wave_id * 64; wbase < N; wbase += nwaves * 64) {
        const long long pm = wbase + l63;       // this lane's own point
        const bool full = (wbase + 64 <= N);

        // ---- all-lane idx load + gather (64 in flight per wave) ----
        uint2 gz8 = make_uint2(0u, 0u);
        if (full || pm < N) {
            int idx;
            if (is64) idx = (int)__builtin_nontemporal_load((const long long*)idx_raw + pm);
            else      idx = __builtin_nontemporal_load((const int*)idx_raw + pm);
            gz8 = GZ8[idx];                     // L2/L3-resident 2MB table
        }

        float r0 = 0.f, r1 = 0.f, r2 = 0.f;

#pragma unroll
        for (int k = 0; k < 8; ++k) {
            const long long pk = wbase + gw8 + k;   // group's point this step
            f32x4 x0, x1;
            if (full || pk < N) {
                const float* prow = pc + (size_t)pk * CPC;
                x0 = nt_load4(prow + 4 * ls);
                x1 = nt_load4(prow + 32 + 4 * ls);
            } else {
                x0 = (f32x4)0.f; x1 = (f32x4)0.f;
            }

            float a0, a1, a2;
            a0 = wA0.x * x0.x;            a1 = wA0.y * x0.x;            a2 = wA0.z * x0.x;
            a0 = fmaf(wA1.x, x0.y, a0);   a1 = fmaf(wA1.y, x0.y, a1);   a2 = fmaf(wA1.z, x0.y, a2);
            a0 = fmaf(wA2.x, x0.z, a0);   a1 = fmaf(wA2.y, x0.z, a1);   a2 = fmaf(wA2.z, x0.z, a2);
            a0 = fmaf(wA3.x, x0.w, a0);   a1 = fmaf(wA3.y, x0.w, a1);   a2 = fmaf(wA3.z, x0.w, a2);
            a0 = fmaf(wB0.x, x1.x, a0);   a1 = fmaf(wB0.y, x1.x, a1);   a2 = fmaf(wB0.z, x1.x, a2);
            a0 = fmaf(wB1.x, x1.y, a0);   a1 = fmaf(wB1.y, x1.y, a1);   a2 = fmaf(wB1.z, x1.y, a2);
            a0 = fmaf(wB2.x, x1.z, a0);   a1 = fmaf(wB2.y, x1.z, a1);   a2 = fmaf(wB2.z, x1.z, a2);
            a0 = fmaf(wB3.x, x1.w, a0);   a1 = fmaf(wB3.y, x1.w, a1);   a2 = fmaf(wB3.z, x1.w, a2);

#pragma unroll
            for (int m = 1; m < 8; m <<= 1) {
                a0 += __shfl_xor(a0, m, 8);
                a1 += __shfl_xor(a1, m, 8);
                a2 += __shfl_xor(a2, m, 8);
            }

            // lane k of the group keeps point k's result (cndmask, no branch)
            if (ls == k) { r0 = a0; r1 = a1; r2 = a2; }
        }

        if (full || pm < N) {
            float* o = out + (size_t)pm * COUT;
            __builtin_nontemporal_store(r0 + bf16_lo(gz8.x), o + 0);
            __builtin_nontemporal_store(r1 + bf16_hi(gz8.x), o + 1);
            __builtin_nontemporal_store(r2 + bf16_lo(gz8.y), o + 2);
        }
    }
}

// ---------------------------------------------------------------------------
// Fallback if workspace < 2 MiB (shouldn't happen). Direct strided gather.
// ---------------------------------------------------------------------------
__global__ void __launch_bounds__(256)
direct_kernel(const float* __restrict__ grid,
              const float* __restrict__ pc,
              const void* __restrict__ idx_raw,
              const float* __restrict__ Yw, const float* __restrict__ Yb,
              const float* __restrict__ Zw, const float* __restrict__ Zb,
              float* __restrict__ out, int N) {
    int i = blockIdx.x * blockDim.x + threadIdx.x;
    if (i >= N) return;
    int idx = (int)(((const long long*)idx_raw)[i]);   // reference spec: int64

    float h[CH];
#pragma unroll
    for (int j = 0; j < CH; ++j) h[j] = Yb[j];
    for (int c = 0; c < CG; ++c) {
        float g = grid[(size_t)c * NCELLS + idx];
#pragma unroll
        for (int j = 0; j < CH; ++j) h[j] = fmaf(Yw[j * CIN + c], g, h[j]);
    }
    const float4* pcp = (const float4*)(pc + (size_t)i * CPC);
#pragma unroll 2
    for (int c4 = 0; c4 < CPC / 4; ++c4) {
        float4 x = pcp[c4];
#pragma unroll
        for (int j = 0; j < CH; ++j) {
            const float* w = Yw + j * CIN + CG + c4 * 4;
            h[j] = fmaf(w[0], x.x, h[j]); h[j] = fmaf(w[1], x.y, h[j]);
            h[j] = fmaf(w[2], x.z, h[j]); h[j] = fmaf(w[3], x.w, h[j]);
        }
    }
#pragma unroll
    for (int t = 0; t < COUT; ++t) {
        float a = Zb[t];
#pragma unroll
        for (int j = 0; j < CH; ++j) a = fmaf(Zw[t * CH + j], h[j], a);
        out[(size_t)i * COUT + t] = a;
    }
}

extern "C" void kernel_launch(void* const* d_in, const int* in_sizes, int n_in,
                              void* d_out, int out_size, void* d_ws, size_t ws_size,
                              hipStream_t stream) {
    const float* grid = (const float*)d_in[0];   // (64,512,512)
    const float* pc   = (const float*)d_in[1];   // (N,64)
    const void*  idx  = d_in[2];                 // (N,) int64 (or int32, detected)
    const float* Yw   = (const float*)d_in[3];   // (32,128)
    const float* Yb   = (const float*)d_in[4];   // (32,)
    const float* Zw   = (const float*)d_in[5];   // (3,32)
    const float* Zb   = (const float*)d_in[6];   // (3,)
    float* out = (float*)d_out;
    const int N = in_sizes[2];

    const size_t GZ_bytes = (size_t)NCELLS * sizeof(uint2);   // 2 MiB

    if (ws_size >= GZ_bytes && N >= 16) {
        uint2* GZ8 = (uint2*)d_ws;
        gz_kernel<<<NCELLS / 256, 256, 0, stream>>>(grid, Yw, Yb, Zw, Zb, GZ8);
        // 2048 blocks = 8192 waves; each wave handles 64 consecutive points
        // per iteration (~1.9 iterations at N=1M).
        main_kernel<<<2048, 256, 0, stream>>>(GZ8, pc, idx, Yw, Zw, out, N);
    } else {
        const int threads = 256;
        direct_kernel<<<(N + threads - 1) / threads, threads, 0, stream>>>(
            grid, pc, idx, Yw, Yb, Zw, Zb, out, N);
    }
}